// Round 6
// baseline (254.606 us; speedup 1.0000x reference)
//
#include <hip/hip_runtime.h>
#include <math.h>

namespace {
constexpr int S  = 256;
constexpr int NT = 256;
constexpr float SCALE = 0.0625f;  // 1/sqrt(256)
}

typedef __bf16 bf16x4 __attribute__((ext_vector_type(4)));
typedef __bf16 bf16x8 __attribute__((ext_vector_type(8)));
typedef float  f32x4  __attribute__((ext_vector_type(4)));

#define MFMA(a, b, c) __builtin_amdgcn_mfma_f32_16x16x32_bf16((a), (b), (c), 0, 0, 0)

// ============ prep: V^T 3-way bf16 split: vth/vtl/vtll[bh][d][t] ============
__global__ __launch_bounds__(NT) void vsplit_kernel(
    const float* __restrict__ v,
    __bf16* __restrict__ vth, __bf16* __restrict__ vtl, __bf16* __restrict__ vtll)
{
    __shared__ float tile[64][65];
    const int tileIdx = blockIdx.x & 15;
    const int bh      = blockIdx.x >> 4;
    const int ti = (tileIdx >> 2) * 64;   // t-origin
    const int tj = (tileIdx & 3) * 64;    // d-origin
    const float* vb = v + (size_t)bh * S * S;

    const int c  = threadIdx.x & 63;
    const int r4 = threadIdx.x >> 6;

    #pragma unroll
    for (int rr = 0; rr < 64; rr += 4)
        tile[rr + r4][c] = vb[(size_t)(ti + rr + r4) * S + tj + c];
    __syncthreads();

    const size_t ob = (size_t)bh * S * S;
    #pragma unroll
    for (int rr = 0; rr < 64; rr += 4) {
        const float x = tile[c][rr + r4];            // v[t=ti+c][d=tj+rr+r4]
        const __bf16 hi = (__bf16)x;
        const float  hf = (float)hi;
        const __bf16 lo = (__bf16)(x - hf);
        const float  lf = (float)lo;
        const __bf16 ll = (__bf16)(x - hf - lf);
        const size_t oi = ob + (size_t)(tj + rr + r4) * S + ti + c;
        vth[oi] = hi; vtl[oi] = lo; vtll[oi] = ll;
    }
}

// ============ prep: K 2-way bf16 split (same [t][i] layout) ============
__global__ __launch_bounds__(NT) void ksplit_kernel(
    const float* __restrict__ k,
    __bf16* __restrict__ kth, __bf16* __restrict__ ktl, size_t n)
{
    const size_t i = ((size_t)blockIdx.x * NT + threadIdx.x) * 4;
    if (i < n) {
        const float4 f = *(const float4*)&k[i];
        const float xs[4] = {f.x, f.y, f.z, f.w};
        bf16x4 hv, lv;
        #pragma unroll
        for (int e = 0; e < 4; ++e) {
            const __bf16 hi = (__bf16)xs[e];
            hv[e] = hi; lv[e] = (__bf16)(xs[e] - (float)hi);
        }
        *(bf16x4*)&kth[i] = hv;
        *(bf16x4*)&ktl[i] = lv;
    }
}

// ============ fused main: QK^T -> (mask+r)@V -> softmax -> P@V ============
// 16 s-rows per block, 2 waves; wave w owns output cols w*128..w*128+127.
__global__ __launch_bounds__(128) void fused16_kernel(
    const float* __restrict__ q, const float* __restrict__ mask,
    const __bf16* __restrict__ kth, const __bf16* __restrict__ ktl,
    const __bf16* __restrict__ vth, const __bf16* __restrict__ vtl,
    const __bf16* __restrict__ vtll,
    float* __restrict__ out, int H, int swz)
{
    __shared__ __align__(16) float  rS[16 * 256];   // fp32 r, swizzled (16 KB)
    __shared__ __align__(16) __bf16 pT[16 * 256];   // P, swizzled (8 KB)
    __shared__ float redmx[2][16];
    __shared__ float redsm[2][16];

    const int tid = threadIdx.x;
    const int w = tid >> 6, l = tid & 63, l15 = l & 15, l4 = l >> 4;
    const int wbase = w * 128;

    int L = blockIdx.x;
    if (swz) L = (blockIdx.x & 7) * ((int)gridDim.x >> 3) + (blockIdx.x >> 3);
    const int bh = L >> 4;
    const int s0 = (L & 15) << 4;
    const int h  = bh % H;

    const size_t hb = (size_t)bh << 16;
    const float* mbase = mask + ((size_t)h << 16);

    // ---- phase 1: r = (scale*Q) K^T  (3-pass split MFMA, B direct-global) ----
    f32x4 acc[8];
    #pragma unroll
    for (int j = 0; j < 8; ++j) acc[j] = (f32x4){0.f, 0.f, 0.f, 0.f};

    {
        const float* qrow = q + hb + (size_t)(s0 + l15) * S;
        for (int kc = 0; kc < 8; ++kc) {
            const float4 f0 = *(const float4*)&qrow[kc * 32 + l4 * 8];
            const float4 f1 = *(const float4*)&qrow[kc * 32 + l4 * 8 + 4];
            const float xs[8] = {f0.x, f0.y, f0.z, f0.w, f1.x, f1.y, f1.z, f1.w};
            bf16x8 qh, ql;
            #pragma unroll
            for (int e = 0; e < 8; ++e) {
                const float x = xs[e] * SCALE;
                const __bf16 hi = (__bf16)x;
                qh[e] = hi; ql[e] = (__bf16)(x - (float)hi);
            }
            #pragma unroll
            for (int j = 0; j < 8; ++j) {
                const size_t ko = hb + (size_t)(wbase + j * 16 + l15) * S + kc * 32 + l4 * 8;
                const bf16x8 kh = *(const bf16x8*)&kth[ko];
                const bf16x8 kl = *(const bf16x8*)&ktl[ko];
                acc[j] = MFMA(qh, kh, acc[j]);
                acc[j] = MFMA(qh, kl, acc[j]);
                acc[j] = MFMA(ql, kh, acc[j]);
            }
        }
    }

    // ---- r -> LDS (fp32, XOR-swizzled: float-idx ^ ((row&7)<<2)) ----
    #pragma unroll
    for (int j = 0; j < 8; ++j) {
        #pragma unroll
        for (int rr = 0; rr < 4; ++rr) {
            const int row = l4 * 4 + rr;
            const int t   = wbase + j * 16 + l15;
            rS[((row << 8) + t) ^ ((row & 7) << 2)] = acc[j][rr];
        }
    }
    __syncthreads();

    // ---- phase 2: acc2 = (mask + r) @ V  (6 split passes, B direct-global) ----
    f32x4 acc2[8];
    #pragma unroll
    for (int j = 0; j < 8; ++j) acc2[j] = (f32x4){0.f, 0.f, 0.f, 0.f};

    {
        const float* mrow = mbase + (size_t)(s0 + l15) * S;
        for (int tc = 0; tc < 8; ++tc) {
            const int cb = tc * 32 + l4 * 8;
            const int X  = (l15 << 8) + cb;
            const int sw = (l15 & 7) << 2;
            // each float4 swizzled independently (16B granule!)
            const float4 r0 = *(const float4*)&rS[X ^ sw];
            const float4 r1 = *(const float4*)&rS[(X + 4) ^ sw];
            const float rs[8] = {r0.x, r0.y, r0.z, r0.w, r1.x, r1.y, r1.z, r1.w};
            bf16x8 rh, rl;
            #pragma unroll
            for (int e = 0; e < 8; ++e) {
                const __bf16 hi = (__bf16)rs[e];
                rh[e] = hi; rl[e] = (__bf16)(rs[e] - (float)hi);
            }
            const float4 m0 = *(const float4*)&mrow[cb];
            const float4 m1 = *(const float4*)&mrow[cb + 4];
            bf16x8 mf;
            mf[0] = (__bf16)m0.x; mf[1] = (__bf16)m0.y;
            mf[2] = (__bf16)m0.z; mf[3] = (__bf16)m0.w;
            mf[4] = (__bf16)m1.x; mf[5] = (__bf16)m1.y;
            mf[6] = (__bf16)m1.z; mf[7] = (__bf16)m1.w;
            #pragma unroll
            for (int j = 0; j < 8; ++j) {
                const size_t vo = hb + (size_t)(wbase + j * 16 + l15) * S + cb;
                const bf16x8 vh  = *(const bf16x8*)&vth[vo];
                const bf16x8 vl  = *(const bf16x8*)&vtl[vo];
                const bf16x8 vll = *(const bf16x8*)&vtll[vo];
                acc2[j] = MFMA(mf, vh,  acc2[j]);
                acc2[j] = MFMA(mf, vl,  acc2[j]);
                acc2[j] = MFMA(mf, vll, acc2[j]);
                acc2[j] = MFMA(rh, vh,  acc2[j]);
                acc2[j] = MFMA(rh, vl,  acc2[j]);
                acc2[j] = MFMA(rl, vh,  acc2[j]);
            }
        }
    }

    // ---- masked fill + cross-wave row softmax ----
    float gm[4];
    #pragma unroll
    for (int rr = 0; rr < 4; ++rr) {
        const int srow = l4 * 4 + rr;
        const float* mr2 = mbase + (size_t)(s0 + srow) * S;
        float mx = -3.4e38f;
        #pragma unroll
        for (int j = 0; j < 8; ++j) {
            const float mval = mr2[wbase + j * 16 + l15];
            const float a = (mval == 0.0f) ? -1e9f : acc2[j][rr];
            acc2[j][rr] = a;
            mx = fmaxf(mx, a);
        }
        #pragma unroll
        for (int off = 1; off < 16; off <<= 1)
            mx = fmaxf(mx, __shfl_xor(mx, off, 64));
        if (l15 == 0) redmx[w][srow] = mx;
    }
    __syncthreads();
    #pragma unroll
    for (int rr = 0; rr < 4; ++rr) {
        const int srow = l4 * 4 + rr;
        gm[rr] = fmaxf(redmx[0][srow], redmx[1][srow]);
        float sm = 0.f;
        #pragma unroll
        for (int j = 0; j < 8; ++j) {
            const float e = __expf(acc2[j][rr] - gm[rr]);
            acc2[j][rr] = e;
            sm += e;
        }
        #pragma unroll
        for (int off = 1; off < 16; off <<= 1)
            sm += __shfl_xor(sm, off, 64);
        if (l15 == 0) redsm[w][srow] = sm;
    }
    __syncthreads();
    #pragma unroll
    for (int rr = 0; rr < 4; ++rr) {
        const int srow = l4 * 4 + rr;
        const float inv = 1.0f / (redsm[0][srow] + redsm[1][srow]);
        #pragma unroll
        for (int j = 0; j < 8; ++j) {
            const int t = wbase + j * 16 + l15;
            pT[((srow << 8) + t) ^ ((srow & 7) << 3)] = (__bf16)(acc2[j][rr] * inv);
        }
    }
    __syncthreads();

    // ---- phase 3: out = P @ V  (p*vh + p*vl) ----
    f32x4 acc3[8];
    #pragma unroll
    for (int j = 0; j < 8; ++j) acc3[j] = (f32x4){0.f, 0.f, 0.f, 0.f};

    for (int tc = 0; tc < 8; ++tc) {
        const int cb = tc * 32 + l4 * 8;
        const int pb = ((l15 << 8) + cb) ^ ((l15 & 7) << 3);
        const bf16x8 pa = *(const bf16x8*)&pT[pb];
        #pragma unroll
        for (int j = 0; j < 8; ++j) {
            const size_t vo = hb + (size_t)(wbase + j * 16 + l15) * S + cb;
            acc3[j] = MFMA(pa, *(const bf16x8*)&vth[vo], acc3[j]);
            acc3[j] = MFMA(pa, *(const bf16x8*)&vtl[vo], acc3[j]);
        }
    }

    float* ob = out + hb + (size_t)s0 * S;
    #pragma unroll
    for (int j = 0; j < 8; ++j) {
        #pragma unroll
        for (int rr = 0; rr < 4; ++rr)
            ob[(size_t)(l4 * 4 + rr) * S + wbase + j * 16 + l15] = acc3[j][rr];
    }
}

// ================= fallback: fp32 path (verified round 2) =================
__global__ __launch_bounds__(NT) void transpose_k_kernel(
    const float* __restrict__ k, float* __restrict__ kt)
{
    __shared__ float tile[64][65];
    const int tileIdx = blockIdx.x & 15;
    const int bh      = blockIdx.x >> 4;
    const int ti = (tileIdx >> 2) * 64;
    const int tj = (tileIdx & 3) * 64;
    const float* kb = k  + (size_t)bh * S * S;
    float*      ktb = kt + (size_t)bh * S * S;
    const int c  = threadIdx.x & 63;
    const int r4 = threadIdx.x >> 6;
    #pragma unroll
    for (int rr = 0; rr < 64; rr += 4)
        tile[rr + r4][c] = kb[(size_t)(ti + rr + r4) * S + tj + c];
    __syncthreads();
    #pragma unroll
    for (int rr = 0; rr < 64; rr += 4)
        ktb[(size_t)(tj + rr + r4) * S + ti + c] = tile[c][rr + r4];
}

template <int RPB>
__global__ __launch_bounds__(NT) void fused_attn_rpb(
    const float* __restrict__ q, const float* __restrict__ kt,
    const float* __restrict__ v, const float* __restrict__ mask,
    float* __restrict__ out, int nbh, int H, int swizzle)
{
    __shared__ float qT[S][RPB];
    __shared__ float sT[S][RPB];
    __shared__ float redbuf[4][RPB];

    const int tid = threadIdx.x;
    constexpr int NRB = S / RPB;
    int bh, rb;
    if (swizzle) {
        const int xcd  = blockIdx.x & 7;
        const int slot = blockIdx.x >> 3;
        const int hpx  = nbh >> 3;
        bh = xcd * hpx + (slot % hpx);
        rb = slot / hpx;
    } else {
        bh = blockIdx.x / NRB;
        rb = blockIdx.x % NRB;
    }
    const int h  = bh % H;
    const int s0 = rb * RPB;

    const float* qb  = q    + (size_t)bh * S * S;
    const float* ktb = kt   + (size_t)bh * S * S;
    const float* vb  = v    + (size_t)bh * S * S;
    const float* mb  = mask + (size_t)h  * S * S + (size_t)s0 * S;
    float*       ob  = out  + (size_t)bh * S * S + (size_t)s0 * S;

    #pragma unroll
    for (int si = 0; si < RPB; ++si)
        qT[tid][si] = qb[(size_t)(s0 + si) * S + tid];
    __syncthreads();

    {
        float acc[RPB];
        #pragma unroll
        for (int si = 0; si < RPB; ++si) acc[si] = 0.f;
        #pragma unroll 4
        for (int i = 0; i < S; ++i) {
            const float kv = ktb[(size_t)i * S + tid];
            #pragma unroll
            for (int si4 = 0; si4 < RPB; si4 += 4) {
                const float4 qa = *reinterpret_cast<const float4*>(&qT[i][si4]);
                acc[si4+0] = fmaf(qa.x, kv, acc[si4+0]);
                acc[si4+1] = fmaf(qa.y, kv, acc[si4+1]);
                acc[si4+2] = fmaf(qa.z, kv, acc[si4+2]);
                acc[si4+3] = fmaf(qa.w, kv, acc[si4+3]);
            }
        }
        #pragma unroll
        for (int si4 = 0; si4 < RPB; si4 += 4) {
            float4 t4;
            t4.x = fmaf(acc[si4+0], SCALE, mb[(size_t)(si4+0)*S + tid]);
            t4.y = fmaf(acc[si4+1], SCALE, mb[(size_t)(si4+1)*S + tid]);
            t4.z = fmaf(acc[si4+2], SCALE, mb[(size_t)(si4+2)*S + tid]);
            t4.w = fmaf(acc[si4+3], SCALE, mb[(size_t)(si4+3)*S + tid]);
            *reinterpret_cast<float4*>(&sT[tid][si4]) = t4;
        }
    }
    __syncthreads();

    float a1[RPB];
    #pragma unroll
    for (int si = 0; si < RPB; ++si) a1[si] = 0.f;
    #pragma unroll 2
    for (int t = 0; t < S; ++t) {
        const float vv = vb[(size_t)t * S + tid];
        #pragma unroll
        for (int si4 = 0; si4 < RPB; si4 += 4) {
            const float4 pa = *reinterpret_cast<const float4*>(&sT[t][si4]);
            a1[si4+0] = fmaf(pa.x, vv, a1[si4+0]);
            a1[si4+1] = fmaf(pa.y, vv, a1[si4+1]);
            a1[si4+2] = fmaf(pa.z, vv, a1[si4+2]);
            a1[si4+3] = fmaf(pa.w, vv, a1[si4+3]);
        }
    }
    #pragma unroll
    for (int si = 0; si < RPB; ++si)
        if (mb[(size_t)si * S + tid] == 0.0f) a1[si] = -1e9f;

    const int lane = tid & 63;
    const int wv   = tid >> 6;
    #pragma unroll
    for (int si = 0; si < RPB; ++si) {
        float m = a1[si];
        #pragma unroll
        for (int off = 32; off > 0; off >>= 1)
            m = fmaxf(m, __shfl_down(m, off, 64));
        if (lane == 0) redbuf[wv][si] = m;
    }
    __syncthreads();
    float e[RPB];
    #pragma unroll
    for (int si = 0; si < RPB; ++si) {
        const float m = fmaxf(fmaxf(redbuf[0][si], redbuf[1][si]),
                              fmaxf(redbuf[2][si], redbuf[3][si]));
        e[si] = __expf(a1[si] - m);
    }
    __syncthreads();
    #pragma unroll
    for (int si = 0; si < RPB; ++si) {
        float sm = e[si];
        #pragma unroll
        for (int off = 32; off > 0; off >>= 1)
            sm += __shfl_down(sm, off, 64);
        if (lane == 0) redbuf[wv][si] = sm;
    }
    __syncthreads();
    #pragma unroll
    for (int si4 = 0; si4 < RPB; si4 += 4) {
        float4 t4;
        #pragma unroll
        for (int jj = 0; jj < 4; ++jj) {
            const int si = si4 + jj;
            const float sm = redbuf[0][si] + redbuf[1][si] +
                             redbuf[2][si] + redbuf[3][si];
            (&t4.x)[jj] = e[si] / sm;
        }
        *reinterpret_cast<float4*>(&sT[tid][si4]) = t4;
    }
    __syncthreads();

    float o[RPB];
    #pragma unroll
    for (int si = 0; si < RPB; ++si) o[si] = 0.f;
    #pragma unroll 2
    for (int t = 0; t < S; ++t) {
        const float vv = vb[(size_t)t * S + tid];
        #pragma unroll
        for (int si4 = 0; si4 < RPB; si4 += 4) {
            const float4 pa = *reinterpret_cast<const float4*>(&sT[t][si4]);
            o[si4+0] = fmaf(pa.x, vv, o[si4+0]);
            o[si4+1] = fmaf(pa.y, vv, o[si4+1]);
            o[si4+2] = fmaf(pa.z, vv, o[si4+2]);
            o[si4+3] = fmaf(pa.w, vv, o[si4+3]);
        }
    }
    #pragma unroll
    for (int si = 0; si < RPB; ++si)
        ob[(size_t)si * S + tid] = o[si];
}

extern "C" void kernel_launch(void* const* d_in, const int* in_sizes, int n_in,
                              void* d_out, int out_size, void* d_ws, size_t ws_size,
                              hipStream_t stream) {
    const float* q    = (const float*)d_in[0];
    const float* k    = (const float*)d_in[1];
    const float* v    = (const float*)d_in[2];
    const float* mask = (const float*)d_in[3];
    float* out = (float*)d_out;

    const int nbh = in_sizes[0] / (S * S);   // B*H
    const int H   = in_sizes[3] / (S * S);   // heads
    const size_t he = (size_t)nbh * S * S;
    const size_t need = he * sizeof(__bf16) * 5;   // vth,vtl,vtll,kth,ktl
    const size_t kt_bytes = he * sizeof(float);

    if (ws_size >= need) {
        __bf16* vth = (__bf16*)d_ws;
        __bf16* vtl = vth + he;
        __bf16* vtll = vtl + he;
        __bf16* kth = vtll + he;
        __bf16* ktl = kth + he;
        const int nblk = nbh * 16;
        const int swz = (nblk % 8 == 0) ? 1 : 0;
        vsplit_kernel<<<dim3(nbh * 16), NT, 0, stream>>>(v, vth, vtl, vtll);
        ksplit_kernel<<<dim3((int)(he / 4 / NT)), NT, 0, stream>>>(k, kth, ktl, he);
        fused16_kernel<<<dim3(nblk), 128, 0, stream>>>(
            q, mask, kth, ktl, vth, vtl, vtll, out, H, swz);
    } else if (ws_size >= kt_bytes) {
        float* kt = (float*)d_ws;
        transpose_k_kernel<<<dim3(nbh * 16), NT, 0, stream>>>(k, kt);
        constexpr int RPB = 16;
        const int grid = nbh * (S / RPB);
        const int swz = (nbh % 8 == 0) ? 1 : 0;
        fused_attn_rpb<RPB><<<dim3(grid), NT, 0, stream>>>(
            q, kt, v, mask, out, nbh, H, swz);
    }
}

// Round 7
// 211.735 us; speedup vs baseline: 1.2025x; 1.2025x over previous
//
#include <hip/hip_runtime.h>
#include <math.h>

namespace {
constexpr int S  = 256;
constexpr int NT = 256;
constexpr float SCALE = 0.0625f;  // 1/sqrt(256)
}

typedef __bf16 bf16x4 __attribute__((ext_vector_type(4)));
typedef __bf16 bf16x8 __attribute__((ext_vector_type(8)));
typedef float  f32x4  __attribute__((ext_vector_type(4)));

#define MFMA(a, b, c) __builtin_amdgcn_mfma_f32_16x16x32_bf16((a), (b), (c), 0, 0, 0)

struct VF3 { bf16x8 h, l, ll; };
struct VF2 { bf16x8 h, l; };

// ============ prep: V^T 3-way bf16 split: vth/vtl/vtll[bh][d][t] ============
__global__ __launch_bounds__(NT) void vsplit_kernel(
    const float* __restrict__ v,
    __bf16* __restrict__ vth, __bf16* __restrict__ vtl, __bf16* __restrict__ vtll)
{
    __shared__ float tile[64][65];
    const int tileIdx = blockIdx.x & 15;
    const int bh      = blockIdx.x >> 4;
    const int ti = (tileIdx >> 2) * 64;   // t-origin
    const int tj = (tileIdx & 3) * 64;    // d-origin
    const float* vb = v + (size_t)bh * S * S;

    const int c  = threadIdx.x & 63;
    const int r4 = threadIdx.x >> 6;

    #pragma unroll
    for (int rr = 0; rr < 64; rr += 4)
        tile[rr + r4][c] = vb[(size_t)(ti + rr + r4) * S + tj + c];
    __syncthreads();

    const size_t ob = (size_t)bh * S * S;
    #pragma unroll
    for (int rr = 0; rr < 64; rr += 4) {
        const float x = tile[c][rr + r4];            // v[t=ti+c][d=tj+rr+r4]
        const __bf16 hi = (__bf16)x;
        const float  hf = (float)hi;
        const __bf16 lo = (__bf16)(x - hf);
        const float  lf = (float)lo;
        const __bf16 ll = (__bf16)(x - hf - lf);
        const size_t oi = ob + (size_t)(tj + rr + r4) * S + ti + c;
        vth[oi] = hi; vtl[oi] = lo; vtll[oi] = ll;
    }
}

// ============ QKT: r = (scale*Q) K^T, 3-pass split MFMA -> r_hi/r_lo ============
__global__ __launch_bounds__(NT) void qkt_kernel(
    const float* __restrict__ q, const float* __restrict__ k,
    __bf16* __restrict__ r_hi, __bf16* __restrict__ r_lo, int swz)
{
    __shared__ __align__(16) __bf16 kh[256 * 40];
    __shared__ __align__(16) __bf16 kl[256 * 40];

    const int tid = threadIdx.x;
    const int w = tid >> 6, l = tid & 63, l15 = l & 15, l4 = l >> 4;

    int L = blockIdx.x;
    if (swz) L = (blockIdx.x & 7) * ((int)gridDim.x >> 3) + (blockIdx.x >> 3);
    const int bh = L >> 2;
    const int s0 = (L & 3) << 6;

    const float* qb = q + ((size_t)bh << 16);
    const float* kb = k + ((size_t)bh << 16);

    // ---- Q rows, pre-scaled, hi/lo split (own 16 rows per wave) ----
    bf16x8 qh[8], ql[8];
    {
        const float* qr = qb + (size_t)(s0 + 16 * w + l15) * S;
        #pragma unroll
        for (int kc = 0; kc < 8; ++kc) {
            const float4 f0 = *(const float4*)&qr[kc * 32 + l4 * 8];
            const float4 f1 = *(const float4*)&qr[kc * 32 + l4 * 8 + 4];
            const float xs[8] = {f0.x, f0.y, f0.z, f0.w, f1.x, f1.y, f1.z, f1.w};
            bf16x8 hv, lv;
            #pragma unroll
            for (int e = 0; e < 8; ++e) {
                const float x = xs[e] * SCALE;
                const __bf16 hi = (__bf16)x;
                hv[e] = hi; lv[e] = (__bf16)(x - (float)hi);
            }
            qh[kc] = hv; ql[kc] = lv;
        }
    }

    f32x4 acc[16];
    #pragma unroll
    for (int j = 0; j < 16; ++j) acc[j] = (f32x4){0.f, 0.f, 0.f, 0.f};

    #pragma unroll
    for (int kc = 0; kc < 8; ++kc) {
        #pragma unroll
        for (int pass = 0; pass < 8; ++pass) {
            const int row = pass * 32 + (tid >> 3);
            const int sub = tid & 7;
            const float4 f = *(const float4*)&kb[(size_t)row * S + kc * 32 + sub * 4];
            const float xs[4] = {f.x, f.y, f.z, f.w};
            bf16x4 hv, lv;
            #pragma unroll
            for (int e = 0; e < 4; ++e) {
                const __bf16 hi = (__bf16)xs[e];
                hv[e] = hi; lv[e] = (__bf16)(xs[e] - (float)hi);
            }
            *(bf16x4*)&kh[row * 40 + sub * 4] = hv;
            *(bf16x4*)&kl[row * 40 + sub * 4] = lv;
        }
        __syncthreads();
        #pragma unroll
        for (int j = 0; j < 16; ++j) {
            const int bo = (j * 16 + l15) * 40 + l4 * 8;
            const bf16x8 khf = *(const bf16x8*)&kh[bo];
            const bf16x8 klf = *(const bf16x8*)&kl[bo];
            acc[j] = MFMA(qh[kc], khf, acc[j]);
            acc[j] = MFMA(qh[kc], klf, acc[j]);
            acc[j] = MFMA(ql[kc], khf, acc[j]);
        }
        __syncthreads();
    }

    __bf16* rh_b = r_hi + ((size_t)bh << 16) + (size_t)s0 * S;
    __bf16* rl_b = r_lo + ((size_t)bh << 16) + (size_t)s0 * S;
    #pragma unroll
    for (int j = 0; j < 16; ++j) {
        #pragma unroll
        for (int rr = 0; rr < 4; ++rr) {
            const int row = 16 * w + l4 * 4 + rr;
            const int t   = j * 16 + l15;
            const float rv = acc[j][rr];
            const __bf16 hi = (__bf16)rv;
            rh_b[(size_t)row * S + t] = hi;
            rl_b[(size_t)row * S + t] = (__bf16)(rv - (float)hi);
        }
    }
}

// ============ attn2: (mask + r)@V -> softmax -> P@V  (reg-pipelined) ============
#define MQ2(Q, BUF, RH, RL, MF)                                         \
    _Pragma("unroll")                                                   \
    for (int jj = 0; jj < 4; ++jj) {                                    \
        acc2[(Q)*4+jj] = MFMA(MF, BUF[jj].h,  acc2[(Q)*4+jj]);          \
        acc2[(Q)*4+jj] = MFMA(MF, BUF[jj].l,  acc2[(Q)*4+jj]);          \
        acc2[(Q)*4+jj] = MFMA(MF, BUF[jj].ll, acc2[(Q)*4+jj]);          \
        acc2[(Q)*4+jj] = MFMA(RH, BUF[jj].h,  acc2[(Q)*4+jj]);          \
        acc2[(Q)*4+jj] = MFMA(RH, BUF[jj].l,  acc2[(Q)*4+jj]);          \
        acc2[(Q)*4+jj] = MFMA(RL, BUF[jj].h,  acc2[(Q)*4+jj]);          \
    }

#define MQ3(Q, BUF, PA)                                                 \
    _Pragma("unroll")                                                   \
    for (int jj = 0; jj < 4; ++jj) {                                    \
        acc3[(Q)*4+jj] = MFMA(PA, BUF[jj].h, acc3[(Q)*4+jj]);           \
        acc3[(Q)*4+jj] = MFMA(PA, BUF[jj].l, acc3[(Q)*4+jj]);           \
    }

__global__ __launch_bounds__(NT, 2) void attn2_kernel(
    const float* __restrict__ mask,
    const __bf16* __restrict__ r_hi, const __bf16* __restrict__ r_lo,
    const __bf16* __restrict__ vth, const __bf16* __restrict__ vtl,
    const __bf16* __restrict__ vtll,
    float* __restrict__ out, int H, int swz)
{
    __shared__ __align__(16) __bf16 pT[64 * 256];   // swizzled P tile (32 KB)

    const int tid = threadIdx.x;
    const int w = tid >> 6, l = tid & 63, l15 = l & 15, l4 = l >> 4;

    int L = blockIdx.x;
    if (swz) L = (blockIdx.x & 7) * ((int)gridDim.x >> 3) + (blockIdx.x >> 3);
    const int bh = L >> 2;
    const int s0 = (L & 3) << 6;
    const int h  = bh % H;

    const size_t hb = (size_t)bh << 16;
    const float* mbase = mask + ((size_t)h << 16);

    const int arow_g = s0 + 16 * w + l15;            // A-frag global row
    const __bf16* rh_p = r_hi + hb + (size_t)arow_g * S;
    const __bf16* rl_p = r_lo + hb + (size_t)arow_g * S;
    const float*  m_p  = mbase + (size_t)arow_g * S;

    // ---- phase 2: acc2 = (mask + r) @ V, register double-buffered ----
    f32x4 acc2[16];
    #pragma unroll
    for (int j = 0; j < 16; ++j) acc2[j] = (f32x4){0.f, 0.f, 0.f, 0.f};

    VF3 b0[4], b1[4];

    auto LDV3 = [&](int tc, int q, VF3* buf) {
        #pragma unroll
        for (int jj = 0; jj < 4; ++jj) {
            const int j = q * 4 + jj;
            const size_t vo = hb + (size_t)(j * 16 + l15) * S + tc * 32 + l4 * 8;
            buf[jj].h  = *(const bf16x8*)&vth[vo];
            buf[jj].l  = *(const bf16x8*)&vtl[vo];
            buf[jj].ll = *(const bf16x8*)&vtll[vo];
        }
    };

    LDV3(0, 0, b0);
    #pragma unroll
    for (int tc = 0; tc < 8; ++tc) {
        const int ko = tc * 32 + l4 * 8;
        const bf16x8 rh = *(const bf16x8*)&rh_p[ko];
        const bf16x8 rl = *(const bf16x8*)&rl_p[ko];
        const float4 m0 = *(const float4*)&m_p[ko];
        const float4 m1 = *(const float4*)&m_p[ko + 4];
        bf16x8 mf;
        mf[0] = (__bf16)m0.x; mf[1] = (__bf16)m0.y;
        mf[2] = (__bf16)m0.z; mf[3] = (__bf16)m0.w;
        mf[4] = (__bf16)m1.x; mf[5] = (__bf16)m1.y;
        mf[6] = (__bf16)m1.z; mf[7] = (__bf16)m1.w;

        LDV3(tc, 1, b1);
        MQ2(0, b0, rh, rl, mf)
        LDV3(tc, 2, b0);
        MQ2(1, b1, rh, rl, mf)
        LDV3(tc, 3, b1);
        MQ2(2, b0, rh, rl, mf)
        LDV3(tc < 7 ? tc + 1 : 7, 0, b0);
        MQ2(3, b1, rh, rl, mf)
    }

    // ---- masked fill + row softmax (in-register, per 16-lane group) ----
    #pragma unroll
    for (int rr = 0; rr < 4; ++rr) {
        const int srow = 16 * w + l4 * 4 + rr;
        const float* mrow = mbase + (size_t)(s0 + srow) * S;
        float mx = -3.4e38f;
        #pragma unroll
        for (int j = 0; j < 16; ++j) {
            const float mval = mrow[j * 16 + l15];
            const float a = (mval == 0.0f) ? -1e9f : acc2[j][rr];
            acc2[j][rr] = a;
            mx = fmaxf(mx, a);
        }
        #pragma unroll
        for (int off = 1; off < 16; off <<= 1)
            mx = fmaxf(mx, __shfl_xor(mx, off, 64));
        float sm = 0.f;
        #pragma unroll
        for (int j = 0; j < 16; ++j) {
            const float e = __expf(acc2[j][rr] - mx);
            acc2[j][rr] = e;
            sm += e;
        }
        #pragma unroll
        for (int off = 1; off < 16; off <<= 1)
            sm += __shfl_xor(sm, off, 64);
        const float inv = 1.0f / sm;
        #pragma unroll
        for (int j = 0; j < 16; ++j) {
            const int t = j * 16 + l15;
            pT[((srow << 8) + t) ^ ((srow & 7) << 3)] = (__bf16)(acc2[j][rr] * inv);
        }
    }
    __syncthreads();

    // ---- phase 3: out = P @ V, register double-buffered ----
    f32x4 acc3[16];
    #pragma unroll
    for (int j = 0; j < 16; ++j) acc3[j] = (f32x4){0.f, 0.f, 0.f, 0.f};

    VF2 c0[4], c1[4];
    auto LDV2 = [&](int tc, int q, VF2* buf) {
        #pragma unroll
        for (int jj = 0; jj < 4; ++jj) {
            const int j = q * 4 + jj;
            const size_t vo = hb + (size_t)(j * 16 + l15) * S + tc * 32 + l4 * 8;
            buf[jj].h = *(const bf16x8*)&vth[vo];
            buf[jj].l = *(const bf16x8*)&vtl[vo];
        }
    };

    const int prow = 16 * w + l15;
    LDV2(0, 0, c0);
    #pragma unroll
    for (int tc = 0; tc < 8; ++tc) {
        const int pb = ((prow << 8) + tc * 32 + l4 * 8) ^ ((prow & 7) << 3);
        const bf16x8 pa = *(const bf16x8*)&pT[pb];

        LDV2(tc, 1, c1);
        MQ3(0, c0, pa)
        LDV2(tc, 2, c0);
        MQ3(1, c1, pa)
        LDV2(tc, 3, c1);
        MQ3(2, c0, pa)
        LDV2(tc < 7 ? tc + 1 : 7, 0, c0);
        MQ3(3, c1, pa)
    }

    float* ob = out + hb + (size_t)s0 * S;
    #pragma unroll
    for (int j = 0; j < 16; ++j) {
        #pragma unroll
        for (int rr = 0; rr < 4; ++rr)
            ob[(size_t)(16 * w + l4 * 4 + rr) * S + j * 16 + l15] = acc3[j][rr];
    }
}

// ================= fallback: fp32 path (verified round 2) =================
__global__ __launch_bounds__(NT) void transpose_k_kernel(
    const float* __restrict__ k, float* __restrict__ kt)
{
    __shared__ float tile[64][65];
    const int tileIdx = blockIdx.x & 15;
    const int bh      = blockIdx.x >> 4;
    const int ti = (tileIdx >> 2) * 64;
    const int tj = (tileIdx & 3) * 64;
    const float* kb = k  + (size_t)bh * S * S;
    float*      ktb = kt + (size_t)bh * S * S;
    const int c  = threadIdx.x & 63;
    const int r4 = threadIdx.x >> 6;
    #pragma unroll
    for (int rr = 0; rr < 64; rr += 4)
        tile[rr + r4][c] = kb[(size_t)(ti + rr + r4) * S + tj + c];
    __syncthreads();
    #pragma unroll
    for (int rr = 0; rr < 64; rr += 4)
        ktb[(size_t)(tj + rr + r4) * S + ti + c] = tile[c][rr + r4];
}

template <int RPB>
__global__ __launch_bounds__(NT) void fused_attn_rpb(
    const float* __restrict__ q, const float* __restrict__ kt,
    const float* __restrict__ v, const float* __restrict__ mask,
    float* __restrict__ out, int nbh, int H, int swizzle)
{
    __shared__ float qT[S][RPB];
    __shared__ float sT[S][RPB];
    __shared__ float redbuf[4][RPB];

    const int tid = threadIdx.x;
    constexpr int NRB = S / RPB;
    int bh, rb;
    if (swizzle) {
        const int xcd  = blockIdx.x & 7;
        const int slot = blockIdx.x >> 3;
        const int hpx  = nbh >> 3;
        bh = xcd * hpx + (slot % hpx);
        rb = slot / hpx;
    } else {
        bh = blockIdx.x / NRB;
        rb = blockIdx.x % NRB;
    }
    const int h  = bh % H;
    const int s0 = rb * RPB;

    const float* qb  = q    + (size_t)bh * S * S;
    const float* ktb = kt   + (size_t)bh * S * S;
    const float* vb  = v    + (size_t)bh * S * S;
    const float* mb  = mask + (size_t)h  * S * S + (size_t)s0 * S;
    float*       ob  = out  + (size_t)bh * S * S + (size_t)s0 * S;

    #pragma unroll
    for (int si = 0; si < RPB; ++si)
        qT[tid][si] = qb[(size_t)(s0 + si) * S + tid];
    __syncthreads();

    {
        float acc[RPB];
        #pragma unroll
        for (int si = 0; si < RPB; ++si) acc[si] = 0.f;
        #pragma unroll 4
        for (int i = 0; i < S; ++i) {
            const float kv = ktb[(size_t)i * S + tid];
            #pragma unroll
            for (int si4 = 0; si4 < RPB; si4 += 4) {
                const float4 qa = *reinterpret_cast<const float4*>(&qT[i][si4]);
                acc[si4+0] = fmaf(qa.x, kv, acc[si4+0]);
                acc[si4+1] = fmaf(qa.y, kv, acc[si4+1]);
                acc[si4+2] = fmaf(qa.z, kv, acc[si4+2]);
                acc[si4+3] = fmaf(qa.w, kv, acc[si4+3]);
            }
        }
        #pragma unroll
        for (int si4 = 0; si4 < RPB; si4 += 4) {
            float4 t4;
            t4.x = fmaf(acc[si4+0], SCALE, mb[(size_t)(si4+0)*S + tid]);
            t4.y = fmaf(acc[si4+1], SCALE, mb[(size_t)(si4+1)*S + tid]);
            t4.z = fmaf(acc[si4+2], SCALE, mb[(size_t)(si4+2)*S + tid]);
            t4.w = fmaf(acc[si4+3], SCALE, mb[(size_t)(si4+3)*S + tid]);
            *reinterpret_cast<float4*>(&sT[tid][si4]) = t4;
        }
    }
    __syncthreads();

    float a1[RPB];
    #pragma unroll
    for (int si = 0; si < RPB; ++si) a1[si] = 0.f;
    #pragma unroll 2
    for (int t = 0; t < S; ++t) {
        const float vv = vb[(size_t)t * S + tid];
        #pragma unroll
        for (int si4 = 0; si4 < RPB; si4 += 4) {
            const float4 pa = *reinterpret_cast<const float4*>(&sT[t][si4]);
            a1[si4+0] = fmaf(pa.x, vv, a1[si4+0]);
            a1[si4+1] = fmaf(pa.y, vv, a1[si4+1]);
            a1[si4+2] = fmaf(pa.z, vv, a1[si4+2]);
            a1[si4+3] = fmaf(pa.w, vv, a1[si4+3]);
        }
    }
    #pragma unroll
    for (int si = 0; si < RPB; ++si)
        if (mb[(size_t)si * S + tid] == 0.0f) a1[si] = -1e9f;

    const int lane = tid & 63;
    const int wv   = tid >> 6;
    #pragma unroll
    for (int si = 0; si < RPB; ++si) {
        float m = a1[si];
        #pragma unroll
        for (int off = 32; off > 0; off >>= 1)
            m = fmaxf(m, __shfl_down(m, off, 64));
        if (lane == 0) redbuf[wv][si] = m;
    }
    __syncthreads();
    float e[RPB];
    #pragma unroll
    for (int si = 0; si < RPB; ++si) {
        const float m = fmaxf(fmaxf(redbuf[0][si], redbuf[1][si]),
                              fmaxf(redbuf[2][si], redbuf[3][si]));
        e[si] = __expf(a1[si] - m);
    }
    __syncthreads();
    #pragma unroll
    for (int si = 0; si < RPB; ++si) {
        float sm = e[si];
        #pragma unroll
        for (int off = 32; off > 0; off >>= 1)
            sm += __shfl_down(sm, off, 64);
        if (lane == 0) redbuf[wv][si] = sm;
    }
    __syncthreads();
    #pragma unroll
    for (int si4 = 0; si4 < RPB; si4 += 4) {
        float4 t4;
        #pragma unroll
        for (int jj = 0; jj < 4; ++jj) {
            const int si = si4 + jj;
            const float sm = redbuf[0][si] + redbuf[1][si] +
                             redbuf[2][si] + redbuf[3][si];
            (&t4.x)[jj] = e[si] / sm;
        }
        *reinterpret_cast<float4*>(&sT[tid][si4]) = t4;
    }
    __syncthreads();

    float o[RPB];
    #pragma unroll
    for (int si = 0; si < RPB; ++si) o[si] = 0.f;
    #pragma unroll 2
    for (int t = 0; t < S; ++t) {
        const float vv = vb[(size_t)t * S + tid];
        #pragma unroll
        for (int si4 = 0; si4 < RPB; si4 += 4) {
            const float4 pa = *reinterpret_cast<const float4*>(&sT[t][si4]);
            o[si4+0] = fmaf(pa.x, vv, o[si4+0]);
            o[si4+1] = fmaf(pa.y, vv, o[si4+1]);
            o[si4+2] = fmaf(pa.z, vv, o[si4+2]);
            o[si4+3] = fmaf(pa.w, vv, o[si4+3]);
        }
    }
    #pragma unroll
    for (int si = 0; si < RPB; ++si)
        ob[(size_t)si * S + tid] = o[si];
}

extern "C" void kernel_launch(void* const* d_in, const int* in_sizes, int n_in,
                              void* d_out, int out_size, void* d_ws, size_t ws_size,
                              hipStream_t stream) {
    const float* q    = (const float*)d_in[0];
    const float* k    = (const float*)d_in[1];
    const float* v    = (const float*)d_in[2];
    const float* mask = (const float*)d_in[3];
    float* out = (float*)d_out;

    const int nbh = in_sizes[0] / (S * S);   // B*H
    const int H   = in_sizes[3] / (S * S);   // heads
    const size_t he = (size_t)nbh * S * S;
    const size_t need = he * sizeof(__bf16) * 5;   // vth,vtl,vtll,r_hi,r_lo
    const size_t kt_bytes = he * sizeof(float);

    if (ws_size >= need) {
        __bf16* vth  = (__bf16*)d_ws;
        __bf16* vtl  = vth + he;
        __bf16* vtll = vtl + he;
        __bf16* rhi  = vtll + he;
        __bf16* rlo  = rhi + he;
        const int nblk = nbh * 4;
        const int swz = (nblk % 8 == 0) ? 1 : 0;
        vsplit_kernel<<<dim3(nbh * 16), NT, 0, stream>>>(v, vth, vtl, vtll);
        qkt_kernel<<<dim3(nblk), NT, 0, stream>>>(q, k, rhi, rlo, swz);
        attn2_kernel<<<dim3(nblk), NT, 0, stream>>>(
            mask, rhi, rlo, vth, vtl, vtll, out, H, swz);
    } else if (ws_size >= kt_bytes) {
        float* kt = (float*)d_ws;
        transpose_k_kernel<<<dim3(nbh * 16), NT, 0, stream>>>(k, kt);
        constexpr int RPB = 16;
        const int grid = nbh * (S / RPB);
        const int swz = (nbh % 8 == 0) ? 1 : 0;
        fused_attn_rpb<RPB><<<dim3(grid), NT, 0, stream>>>(
            q, kt, v, mask, out, nbh, H, swz);
    }
}